// Round 6
// baseline (86.466 us; speedup 1.0000x reference)
//
#include <hip/hip_runtime.h>

// PatcherUnfold: y[b,l,e] = sum_k patches[b,l,k] * W[e,k] + bias[e]
// Implicit GEMM, M=36864 N=768 K=768, bf16 MFMA 16x16x32, fp32 accum.
// Round 6: m97-style structure — 128x128 tile, BK=32, 4 waves, single 16 KiB
// LDS buffer, 3 blocks/CU co-residency (the stall-hiding mechanism), A
// reg-staged fp32->bf16 issued-early, B via global_load_lds w/ pre-swizzled
// source, W pre-converted bf16, XCD-chunked block swizzle.

namespace {

constexpr int PB   = 16;
constexpr int Cch  = 3;
constexpr int Him  = 384;
constexpr int Wim  = 384;
constexpr int GWp  = 24;
constexpr int Lp   = 576;
constexpr int Kd   = 768;
constexpr int Nd   = 768;
constexpr int Md   = 64 * Lp;        // 36864
constexpr int BM   = 128;
constexpr int BN   = 128;
constexpr int BK   = 32;
constexpr int NT   = Kd / BK;        // 24
constexpr int GN   = Nd / BN;        // 6
constexpr int NBLK = (Md / BM) * GN; // 1728 = 8 * 216

typedef __bf16 bf16x4 __attribute__((ext_vector_type(4)));
typedef __bf16 bf16x8 __attribute__((ext_vector_type(8)));
typedef float  f32x4  __attribute__((ext_vector_type(4)));

__global__ __launch_bounds__(256)
void convert_w(const float* __restrict__ Wm, __bf16* __restrict__ Wb)
{
    const int i = (blockIdx.x * 256 + threadIdx.x) * 4;
    const f32x4 v = *(const f32x4*)(Wm + i);
    bf16x4 h;
    #pragma unroll
    for (int e = 0; e < 4; ++e) h[e] = (__bf16)v[e];
    *(bf16x4*)(Wb + i) = h;
}

__device__ __forceinline__ void gload_lds16(const void* gsrc, void* lds_dst)
{
    __builtin_amdgcn_global_load_lds(
        (const __attribute__((address_space(1))) unsigned int*)gsrc,
        (__attribute__((address_space(3))) unsigned int*)lds_dst,
        16, 0, 0);
}

__global__ __launch_bounds__(256, 3)
void patch_embed_gemm(const float* __restrict__ x,
                      const __bf16* __restrict__ Wb,
                      const float* __restrict__ bias,
                      float* __restrict__ out)
{
    // single buffer: A 128x32 bf16 (8 KiB) | B 128x32 bf16 (8 KiB)
    __shared__ __align__(16) unsigned char lds[16384];
    unsigned char* const ldsA = lds;
    unsigned char* const ldsB = lds + 8192;

    // XCD-chunked swizzle (1728 % 8 == 0 -> bijective), bm-major so the 6
    // blocks sharing an A-panel are id-adjacent on one XCD.
    const int h  = blockIdx.x;
    const int l  = (h & 7) * (NBLK / 8) + (h >> 3);
    const int bm = l / GN;
    const int bn = l - bm * GN;

    const int tid  = threadIdx.x;
    const int lane = tid & 63;
    const int wv   = tid >> 6;   // 0..3
    const int wr   = wv >> 1;    // 0..1 -> 64-row strip
    const int wc   = wv & 1;     // 0..1 -> 64-col strip
    const int fr   = lane & 15;
    const int kg   = lane >> 4;

    // ---- A staging map: thread covers rows (tid>>3) + 32*it, chunk cq
    const int r0   = tid >> 3;   // 0..31
    const int cq   = tid & 7;    // 8 f32x4 chunks per 32-float row
    const int pxy  = (cq >> 2) * Wim + (cq & 3) * 4;   // within 2 patch-rows
    const int swzA = ((r0 & 3) << 4);
    unsigned char* const ldsA_w = ldsA + r0 * 64 + ((cq * 8) ^ swzA);

    int arow[4];
    #pragma unroll
    for (int it = 0; it < 4; ++it) {
        const int m  = bm * BM + r0 + it * 32;
        const int b  = m / Lp;
        const int li = m - b * Lp;
        const int gy = li / GWp;
        const int gx = li - gy * GWp;
        arow[it] = b * (Cch * Him * Wim) + (gy * PB) * Wim + gx * PB;
    }

    // ---- B staging map (global_load_lds, linear LDS dest, swizzled source)
    const unsigned char* wbB = (const unsigned char*)(Wb + (size_t)(bn * BN) * Kd);
    int boff[2], bdst[2];
    #pragma unroll
    for (int it = 0; it < 2; ++it) {
        const int i    = it * 256 + tid;  // 16-B unit index
        const int row  = i >> 2;
        const int slot = i & 3;
        boff[it] = row * (Kd * 2) + ((slot ^ (row & 3)) << 4);
        bdst[it] = i * 16;
    }

    f32x4 paA[4], paB[4];

    auto load_A = [&](f32x4 (&pa)[4], int t) {
        const int c   = t >> 3;        // 8 K-steps per channel
        const int pyb = (t & 7) * 2;   // first of 2 patch-rows
        const float* xs = x + c * (Him * Wim) + pyb * Wim + pxy;
        #pragma unroll
        for (int it = 0; it < 4; ++it)
            pa[it] = *(const f32x4*)(xs + arow[it]);
    };

    auto store_A = [&](f32x4 (&pa)[4]) {
        #pragma unroll
        for (int it = 0; it < 4; ++it) {
            bf16x4 ha;
            #pragma unroll
            for (int e = 0; e < 4; ++e) ha[e] = (__bf16)pa[it][e];
            *(bf16x4*)(ldsA_w + it * 2048) = ha;   // 32 rows * 64 B
        }
    };

    auto stage_B = [&](int t) {
        const unsigned char* src = wbB + t * 64;
        gload_lds16(src + boff[0], ldsB + bdst[0]);
        gload_lds16(src + boff[1], ldsB + bdst[1]);
    };

    f32x4 acc[4][4];
    #pragma unroll
    for (int i = 0; i < 4; ++i)
        #pragma unroll
        for (int j = 0; j < 4; ++j)
            acc[i][j] = f32x4{0.f, 0.f, 0.f, 0.f};

    // fragment read offsets: row*64 + (kg*16 ^ ((row&3)<<4)), row&3 == fr&3
    const int abase = (wr * 64 + fr) * 64 + ((kg * 16) ^ ((fr & 3) << 4));
    const int bbase = (wc * 64 + fr) * 64 + ((kg * 16) ^ ((fr & 3) << 4));

    auto compute = [&]() {
        bf16x8 br[4];
        #pragma unroll
        for (int fj = 0; fj < 4; ++fj)
            br[fj] = *(const bf16x8*)(ldsB + bbase + fj * 1024);
        #pragma unroll
        for (int fi = 0; fi < 4; ++fi) {
            const bf16x8 ar = *(const bf16x8*)(ldsA + abase + fi * 1024);
            #pragma unroll
            for (int fj = 0; fj < 4; ++fj)
                acc[fi][fj] = __builtin_amdgcn_mfma_f32_16x16x32_bf16(
                    ar, br[fj], acc[fi][fj], 0, 0, 0);
        }
    };

    // ---- main loop: single LDS buffer, 2 barriers/step, issue-early A loads
    load_A(paA, 0);
    for (int t = 0; t < NT; t += 2) {
        __syncthreads();               // everyone done reading tile t-1
        store_A(paA);
        stage_B(t);
        __syncthreads();               // tile t visible (drains B DMA)
        load_A(paB, t + 1);            // in flight under compute(t)
        compute();

        __syncthreads();
        store_A(paB);
        stage_B(t + 1);
        __syncthreads();
        if (t + 2 < NT) load_A(paA, t + 2);
        compute();
    }

    // epilogue: C/D layout col = lane&15, row = (lane>>4)*4 + j
    const int orow0 = bm * BM + wr * 64;
    const int ocol0 = bn * BN + wc * 64;
    #pragma unroll
    for (int fj = 0; fj < 4; ++fj) {
        const int col = ocol0 + fj * 16 + fr;
        const float bv = bias[col];
        #pragma unroll
        for (int fi = 0; fi < 4; ++fi) {
            const int row = orow0 + fi * 16 + kg * 4;
            #pragma unroll
            for (int j = 0; j < 4; ++j)
                out[(row + j) * Nd + col] = acc[fi][fj][j] + bv;
        }
    }
}

} // namespace

extern "C" void kernel_launch(void* const* d_in, const int* in_sizes, int n_in,
                              void* d_out, int out_size, void* d_ws, size_t ws_size,
                              hipStream_t stream)
{
    (void)in_sizes; (void)n_in; (void)out_size; (void)ws_size;
    const float* x  = (const float*)d_in[0];
    const float* Wm = (const float*)d_in[1];
    const float* bs = (const float*)d_in[2];
    float* outp = (float*)d_out;
    __bf16* Wb = (__bf16*)d_ws;   // 1.13 MiB

    convert_w<<<dim3(Kd * Nd / 1024), dim3(256), 0, stream>>>(Wm, Wb);
    patch_embed_gemm<<<dim3(NBLK), dim3(256), 0, stream>>>(x, Wb, bs, outp);
}

// Round 8
// 81.483 us; speedup vs baseline: 1.0612x; 1.0612x over previous
//
#include <hip/hip_runtime.h>

// PatcherUnfold: y[b,l,e] = sum_k patches[b,l,k] * W[e,k] + bias[e]
// Implicit GEMM, M=36864 N=768 K=768, bf16 MFMA 16x16x32, fp32 accum.
// Round 8: Round-7 structure (m97-style: 128x128 tile, BK=64, single 32 KiB
// LDS buffer, 2 barriers/K-step, 3 blocks/CU) with the fragment-read address
// bug fixed: XOR swizzle applied to the FULL within-row offset
// (kk*64+kg*16) ^ ((fr&7)<<4) — hoisting the XOR caused a bit-6 carry into
// the row index for fr&4 lanes (R7 absmax 12).

namespace {

constexpr int PB   = 16;
constexpr int Cch  = 3;
constexpr int Him  = 384;
constexpr int Wim  = 384;
constexpr int GWp  = 24;
constexpr int Lp   = 576;
constexpr int Kd   = 768;
constexpr int Nd   = 768;
constexpr int Md   = 64 * Lp;        // 36864
constexpr int BM   = 128;
constexpr int BN   = 128;
constexpr int BK   = 64;
constexpr int NT   = Kd / BK;        // 12
constexpr int GN   = Nd / BN;        // 6
constexpr int NBLK = (Md / BM) * GN; // 1728 = 8 * 216

typedef __bf16 bf16x4 __attribute__((ext_vector_type(4)));
typedef __bf16 bf16x8 __attribute__((ext_vector_type(8)));
typedef float  f32x4  __attribute__((ext_vector_type(4)));

__global__ __launch_bounds__(256)
void convert_w(const float* __restrict__ Wm, __bf16* __restrict__ Wb)
{
    const int i = (blockIdx.x * 256 + threadIdx.x) * 4;
    const f32x4 v = *(const f32x4*)(Wm + i);
    bf16x4 h;
    #pragma unroll
    for (int e = 0; e < 4; ++e) h[e] = (__bf16)v[e];
    *(bf16x4*)(Wb + i) = h;
}

__device__ __forceinline__ void gload_lds16(const void* gsrc, void* lds_dst)
{
    __builtin_amdgcn_global_load_lds(
        (const __attribute__((address_space(1))) unsigned int*)gsrc,
        (__attribute__((address_space(3))) unsigned int*)lds_dst,
        16, 0, 0);
}

__global__ __launch_bounds__(256, 3)
void patch_embed_gemm(const float* __restrict__ x,
                      const __bf16* __restrict__ Wb,
                      const float* __restrict__ bias,
                      float* __restrict__ out)
{
    // single buffer: A 128x64 bf16 (16 KiB) | B 128x64 bf16 (16 KiB)
    __shared__ __align__(16) unsigned char lds[32768];
    unsigned char* const ldsA = lds;
    unsigned char* const ldsB = lds + 16384;

    // XCD-chunked swizzle (1728 % 8 == 0 -> bijective), bm-major so the 6
    // blocks sharing an A-panel are id-adjacent on one XCD.
    const int h  = blockIdx.x;
    const int l  = (h & 7) * (NBLK / 8) + (h >> 3);
    const int bm = l / GN;
    const int bn = l - bm * GN;

    const int tid  = threadIdx.x;
    const int lane = tid & 63;
    const int wv   = tid >> 6;   // 0..3
    const int wr   = wv >> 1;    // 0..1 -> 64-row strip
    const int wc   = wv & 1;     // 0..1 -> 64-col strip
    const int fr   = lane & 15;
    const int kg   = lane >> 4;

    // ---- A staging map: thread covers rows r0 + 16*it (it=0..7), chunk q
    const int q    = tid & 15;   // 16 f32x4 chunks per 64-float row
    const int r0   = tid >> 4;   // 0..15
    const int px   = (q & 3) * 4;
    const int pyo  = q >> 2;
    // 128-B rows, proven swizzle: byte ^= (row&7)<<4 (row&7 == r0&7, it*16 rows)
    unsigned char* const ldsA_w = ldsA + r0 * 128 + ((q * 8) ^ ((r0 & 7) << 4));

    int arow[8];
    #pragma unroll
    for (int it = 0; it < 8; ++it) {
        const int m  = bm * BM + r0 + it * 16;
        const int b  = m / Lp;
        const int li = m - b * Lp;
        const int gy = li / GWp;
        const int gx = li - gy * GWp;
        arow[it] = b * (Cch * Him * Wim) + (gy * PB) * Wim + gx * PB;
    }

    // ---- B staging map (global_load_lds, linear LDS dest, swizzled source)
    const unsigned char* wbB = (const unsigned char*)(Wb + (size_t)(bn * BN) * Kd);
    int boff[4], bdst[4];
    #pragma unroll
    for (int j = 0; j < 4; ++j) {
        const int off = (j * 256 + tid) * 16;  // dest byte offset
        const int row = off >> 7;              // 0..127
        const int bb  = off & 127;
        boff[j] = row * (Kd * 2) + (bb ^ ((row & 7) << 4));
        bdst[j] = off;
    }

    f32x4 pa[8];

    auto load_A = [&](int t) {
        const int c   = t >> 2;        // channel (4 K-steps per channel)
        const int pyb = (t & 3) * 4;   // first of 4 patch-rows
        const float* xs = x + c * (Him * Wim) + (pyb + pyo) * Wim + px;
        #pragma unroll
        for (int it = 0; it < 8; ++it)
            pa[it] = *(const f32x4*)(xs + arow[it]);
    };

    auto store_A = [&]() {
        #pragma unroll
        for (int it = 0; it < 8; ++it) {
            bf16x4 ha;
            #pragma unroll
            for (int e = 0; e < 4; ++e) ha[e] = (__bf16)pa[it][e];
            *(bf16x4*)(ldsA_w + it * 2048) = ha;   // 16 rows * 128 B
        }
    };

    auto stage_B = [&](int t) {
        const unsigned char* src = wbB + t * 128;
        #pragma unroll
        for (int j = 0; j < 4; ++j)
            gload_lds16(src + boff[j], ldsB + bdst[j]);
    };

    f32x4 acc[4][4];
    #pragma unroll
    for (int i = 0; i < 4; ++i)
        #pragma unroll
        for (int j = 0; j < 4; ++j)
            acc[i][j] = f32x4{0.f, 0.f, 0.f, 0.f};

    // fragment row bases; swizzle applied per-(kk) to the FULL byte offset
    const int arowb = (wr * 64 + fr) * 128;
    const int browb = (wc * 64 + fr) * 128;
    const int sw    = (fr & 7) << 4;

    auto compute = [&]() {
        #pragma unroll
        for (int kk = 0; kk < 2; ++kk) {
            const int kb = (kk * 64 + kg * 16) ^ sw;   // bits 4-6 only
            bf16x8 br[4];
            #pragma unroll
            for (int fj = 0; fj < 4; ++fj)
                br[fj] = *(const bf16x8*)(ldsB + browb + fj * 2048 + kb);
            #pragma unroll
            for (int fi = 0; fi < 4; ++fi) {
                const bf16x8 ar = *(const bf16x8*)(ldsA + arowb + fi * 2048 + kb);
                #pragma unroll
                for (int fj = 0; fj < 4; ++fj)
                    acc[fi][fj] = __builtin_amdgcn_mfma_f32_16x16x32_bf16(
                        ar, br[fj], acc[fi][fj], 0, 0, 0);
            }
        }
    };

    // ---- main loop: m97 structure, 2 barriers/step, issue-early A loads ----
    load_A(0);
    for (int t = 0; t < NT; ++t) {
        __syncthreads();               // all reads of tile t-1 done
        store_A();                     // cvt + ds_write A(t)
        stage_B(t);                    // DMA B(t)
        __syncthreads();               // tile t visible (drains DMA + writes)
        if (t + 1 < NT) load_A(t + 1); // in flight under compute(t)
        compute();
    }

    // epilogue: C/D layout col = lane&15, row = (lane>>4)*4 + j
    const int orow0 = bm * BM + wr * 64;
    const int ocol0 = bn * BN + wc * 64;
    #pragma unroll
    for (int fj = 0; fj < 4; ++fj) {
        const int col = ocol0 + fj * 16 + fr;
        const float bv = bias[col];
        #pragma unroll
        for (int fi = 0; fi < 4; ++fi) {
            const int row = orow0 + fi * 16 + kg * 4;
            #pragma unroll
            for (int j = 0; j < 4; ++j)
                out[(row + j) * Nd + col] = acc[fi][fj][j] + bv;
        }
    }
}

} // namespace

extern "C" void kernel_launch(void* const* d_in, const int* in_sizes, int n_in,
                              void* d_out, int out_size, void* d_ws, size_t ws_size,
                              hipStream_t stream)
{
    (void)in_sizes; (void)n_in; (void)out_size; (void)ws_size;
    const float* x  = (const float*)d_in[0];
    const float* Wm = (const float*)d_in[1];
    const float* bs = (const float*)d_in[2];
    float* outp = (float*)d_out;
    __bf16* Wb = (__bf16*)d_ws;   // 1.13 MiB

    convert_w<<<dim3(Kd * Nd / 1024), dim3(256), 0, stream>>>(Wm, Wb);
    patch_embed_gemm<<<dim3(NBLK), dim3(256), 0, stream>>>(x, Wb, bs, outp);
}

// Round 9
// 71.929 us; speedup vs baseline: 1.2021x; 1.1328x over previous
//
#include <hip/hip_runtime.h>

// PatcherUnfold: y[b,l,e] = sum_k patches[b,l,k] * W[e,k] + bias[e]
// Implicit GEMM, M=36864 N=768 K=768, bf16 MFMA 16x16x32, fp32 accum.
// Round 9: B never touches LDS — W is pre-packed (d_ws) into MFMA-fragment
// order (1024 B contiguous per wave-fragment) and loaded straight from L2
// with one global_load_dwordx4 per fragment. Wave layout 1x4 (wave-tile
// 128x64, block 128x256): halves LDS-read/FLOP, no B duplication, x re-read
// 6x->3x. A reg-staged fp32->bf16 into single 16 KiB LDS buffer (R8-proven
// swizzle), 2 barriers/K-step, XCD-chunked block swizzle (864 = 8*108).

namespace {

constexpr int PB   = 16;
constexpr int Cch  = 3;
constexpr int Him  = 384;
constexpr int Wim  = 384;
constexpr int GWp  = 24;
constexpr int Lp   = 576;
constexpr int Kd   = 768;
constexpr int Nd   = 768;
constexpr int Md   = 64 * Lp;        // 36864
constexpr int BM   = 128;
constexpr int BN   = 256;
constexpr int BK   = 64;
constexpr int NT   = Kd / BK;        // 12
constexpr int GN   = Nd / BN;        // 3
constexpr int NBLK = (Md / BM) * GN; // 864 = 8 * 108
constexpr int NKC  = Kd / 32;        // 24 k-chunks per col-group

typedef __bf16 bf16x4 __attribute__((ext_vector_type(4)));
typedef __bf16 bf16x8 __attribute__((ext_vector_type(8)));
typedef float  f32x4  __attribute__((ext_vector_type(4)));

// Pack W[768][768] fp32 -> fragment-ordered bf16:
// fragment (g, kc): 64 lanes x 8 bf16 contiguous (1024 B); lane l holds
// W[g*16 + (l&15)][kc*32 + (l>>4)*8 .. +8].  addr elem = ((g*NKC+kc)*64+l)*8
__global__ __launch_bounds__(256)
void pack_w(const float* __restrict__ Wm, __bf16* __restrict__ Wf)
{
    const int gid  = blockIdx.x * 256 + threadIdx.x;  // 0..73727
    const int frag = gid >> 6;
    const int lane = gid & 63;
    const int g    = frag / NKC;
    const int kc   = frag - g * NKC;
    const float* src = Wm + (g * 16 + (lane & 15)) * Kd + kc * 32 + (lane >> 4) * 8;
    const f32x4 v0 = *(const f32x4*)src;
    const f32x4 v1 = *(const f32x4*)(src + 4);
    bf16x8 h;
    #pragma unroll
    for (int e = 0; e < 4; ++e) { h[e] = (__bf16)v0[e]; h[4 + e] = (__bf16)v1[e]; }
    *(bf16x8*)(Wf + (size_t)gid * 8) = h;
}

__global__ __launch_bounds__(256, 2)
void patch_embed_gemm(const float* __restrict__ x,
                      const __bf16* __restrict__ Wf,
                      const float* __restrict__ bias,
                      float* __restrict__ out)
{
    // A only: 128 x 64 bf16, 128-B rows, XOR-swizzled (16 KiB)
    __shared__ __align__(16) unsigned char ldsA[BM * BK * 2];

    // XCD-chunked swizzle (864 % 8 == 0 -> bijective), bm-major.
    const int h  = blockIdx.x;
    const int l  = (h & 7) * (NBLK / 8) + (h >> 3);
    const int bm = l / GN;
    const int bn = l - bm * GN;

    const int tid  = threadIdx.x;
    const int lane = tid & 63;
    const int wc   = tid >> 6;   // 0..3 -> 64-col strip (1x4 layout)
    const int fr   = lane & 15;
    const int kg   = lane >> 4;

    // ---- A staging map (identical to R8): rows r0 + 16*it, chunk q
    const int q    = tid & 15;
    const int r0   = tid >> 4;
    const int px   = (q & 3) * 4;
    const int pyo  = q >> 2;
    unsigned char* const ldsA_w = ldsA + r0 * 128 + ((q * 8) ^ ((r0 & 7) << 4));

    int arow[8];
    #pragma unroll
    for (int it = 0; it < 8; ++it) {
        const int m  = bm * BM + r0 + it * 16;
        const int b  = m / Lp;
        const int li = m - b * Lp;
        const int gy = li / GWp;
        const int gx = li - gy * GWp;
        arow[it] = b * (Cch * Him * Wim) + (gy * PB) * Wim + gx * PB;
    }

    // ---- B fragment base: col-groups g = bn*16 + wc*4 + fj, k-chunk t*2+kk
    const __bf16* const wfw = Wf + ((size_t)(bn * 16 + wc * 4) * NKC) * 512 + lane * 8;

    f32x4 pa[8];

    auto load_A = [&](int t) {
        const int c   = t >> 2;
        const int pyb = (t & 3) * 4;
        const float* xs = x + c * (Him * Wim) + (pyb + pyo) * Wim + px;
        #pragma unroll
        for (int it = 0; it < 8; ++it)
            pa[it] = *(const f32x4*)(xs + arow[it]);
    };

    auto store_A = [&]() {
        #pragma unroll
        for (int it = 0; it < 8; ++it) {
            bf16x4 ha;
            #pragma unroll
            for (int e = 0; e < 4; ++e) ha[e] = (__bf16)pa[it][e];
            *(bf16x4*)(ldsA_w + it * 2048) = ha;
        }
    };

    f32x4 acc[8][4];
    #pragma unroll
    for (int i = 0; i < 8; ++i)
        #pragma unroll
        for (int j = 0; j < 4; ++j)
            acc[i][j] = f32x4{0.f, 0.f, 0.f, 0.f};

    const int arowb = fr * 128;
    const int sw    = (fr & 7) << 4;

    auto compute = [&](int t) {
        // B fragments straight from L2 (8 coalesced 1024-B loads)
        bf16x8 br[4][2];
        #pragma unroll
        for (int fj = 0; fj < 4; ++fj)
            #pragma unroll
            for (int kk = 0; kk < 2; ++kk)
                br[fj][kk] = *(const bf16x8*)(wfw + (fj * NKC + t * 2 + kk) * 512);
        #pragma unroll
        for (int kk = 0; kk < 2; ++kk) {
            const int kb = (kk * 64 + kg * 16) ^ sw;   // bits 4-6 only
            #pragma unroll
            for (int fi = 0; fi < 8; ++fi) {
                const bf16x8 ar = *(const bf16x8*)(ldsA + arowb + fi * 2048 + kb);
                #pragma unroll
                for (int fj = 0; fj < 4; ++fj)
                    acc[fi][fj] = __builtin_amdgcn_mfma_f32_16x16x32_bf16(
                        ar, br[fj][kk], acc[fi][fj], 0, 0, 0);
            }
        }
    };

    // ---- main loop: single A buffer, 2 barriers/K-step, issue-early loads
    load_A(0);
    for (int t = 0; t < NT; ++t) {
        __syncthreads();               // all reads of tile t-1 done
        store_A();                     // cvt + ds_write A(t)
        __syncthreads();               // A(t) visible
        if (t + 1 < NT) load_A(t + 1); // global->regs, in flight under compute
        compute(t);
    }

    // epilogue: C/D layout col = lane&15, row = (lane>>4)*4 + j
    const int orow0 = bm * BM;
    const int ocol0 = bn * BN + wc * 64;
    #pragma unroll
    for (int fj = 0; fj < 4; ++fj) {
        const int col = ocol0 + fj * 16 + fr;
        const float bv = bias[col];
        #pragma unroll
        for (int fi = 0; fi < 8; ++fi) {
            const int row = orow0 + fi * 16 + kg * 4;
            #pragma unroll
            for (int j = 0; j < 4; ++j)
                out[(row + j) * Nd + col] = acc[fi][fj][j] + bv;
        }
    }
}

} // namespace

extern "C" void kernel_launch(void* const* d_in, const int* in_sizes, int n_in,
                              void* d_out, int out_size, void* d_ws, size_t ws_size,
                              hipStream_t stream)
{
    (void)in_sizes; (void)n_in; (void)out_size; (void)ws_size;
    const float* x  = (const float*)d_in[0];
    const float* Wm = (const float*)d_in[1];
    const float* bs = (const float*)d_in[2];
    float* outp = (float*)d_out;
    __bf16* Wf = (__bf16*)d_ws;   // 768*768*2 B, fragment-ordered

    pack_w<<<dim3(Kd * Nd / (256 * 8)), dim3(256), 0, stream>>>(Wm, Wf);
    patch_embed_gemm<<<dim3(NBLK), dim3(256), 0, stream>>>(x, Wf, bs, outp);
}

// Round 10
// 70.847 us; speedup vs baseline: 1.2205x; 1.0153x over previous
//
#include <hip/hip_runtime.h>

// PatcherUnfold: y[b,l,e] = sum_k patches[b,l,k] * W[e,k] + bias[e]
// Implicit GEMM, M=36864 N=768 K=768, bf16 MFMA 16x16x32, fp32 accum.
// Round 10: block 64x384 (4 waves, wave tile 64x96). GN=2 halves x L3
// re-reads; acc=96 + per-kk B loads -> ~160 regs -> 3 waves/SIMD (3 blocks/CU
// co-residency). B from L2 via fragment-packed W (d_ws, R9); A reg-staged
// fp32->bf16 into single 8 KiB LDS buffer (R8-proven swizzle), 2 barriers/
// K-step, XCD-chunked bijective swizzle (1152 = 8*144, bm-major).

namespace {

constexpr int PB   = 16;
constexpr int Cch  = 3;
constexpr int Him  = 384;
constexpr int Wim  = 384;
constexpr int GWp  = 24;
constexpr int Lp   = 576;
constexpr int Kd   = 768;
constexpr int Nd   = 768;
constexpr int Md   = 64 * Lp;        // 36864
constexpr int BM   = 64;
constexpr int BN   = 384;
constexpr int BK   = 64;
constexpr int NT   = Kd / BK;        // 12
constexpr int GN   = Nd / BN;        // 2
constexpr int NBLK = (Md / BM) * GN; // 1152 = 8 * 144
constexpr int NKC  = Kd / 32;        // 24 k-chunks per 16-col group

typedef __bf16 bf16x4 __attribute__((ext_vector_type(4)));
typedef __bf16 bf16x8 __attribute__((ext_vector_type(8)));
typedef float  f32x4  __attribute__((ext_vector_type(4)));

// Pack W[768][768] fp32 -> fragment-ordered bf16 (as R9):
// fragment (g, kc): 64 lanes x 8 bf16 contiguous (1024 B); lane l holds
// W[g*16 + (l&15)][kc*32 + (l>>4)*8 .. +8].
__global__ __launch_bounds__(256)
void pack_w(const float* __restrict__ Wm, __bf16* __restrict__ Wf)
{
    const int gid  = blockIdx.x * 256 + threadIdx.x;  // 0..73727
    const int frag = gid >> 6;
    const int lane = gid & 63;
    const int g    = frag / NKC;
    const int kc   = frag - g * NKC;
    const float* src = Wm + (g * 16 + (lane & 15)) * Kd + kc * 32 + (lane >> 4) * 8;
    const f32x4 v0 = *(const f32x4*)src;
    const f32x4 v1 = *(const f32x4*)(src + 4);
    bf16x8 h;
    #pragma unroll
    for (int e = 0; e < 4; ++e) { h[e] = (__bf16)v0[e]; h[4 + e] = (__bf16)v1[e]; }
    *(bf16x8*)(Wf + (size_t)gid * 8) = h;
}

__global__ __launch_bounds__(256, 3)
void patch_embed_gemm(const float* __restrict__ x,
                      const __bf16* __restrict__ Wf,
                      const float* __restrict__ bias,
                      float* __restrict__ out)
{
    // A only: 64 x 64 bf16, 128-B rows, XOR-swizzled (8 KiB)
    __shared__ __align__(16) unsigned char ldsA[BM * BK * 2];

    // XCD-chunked swizzle (1152 % 8 == 0 -> bijective), bm-major: the 2
    // blocks sharing an A-panel are id-adjacent -> concurrent on one XCD.
    const int h  = blockIdx.x;
    const int l  = (h & 7) * (NBLK / 8) + (h >> 3);
    const int bm = l >> 1;
    const int bn = l & 1;

    const int tid  = threadIdx.x;
    const int lane = tid & 63;
    const int wc   = tid >> 6;   // 0..3 -> 96-col strip
    const int fr   = lane & 15;
    const int kg   = lane >> 4;

    // ---- A staging map: rows r0 + 16*it (it=0..3), chunk q
    const int q    = tid & 15;
    const int r0   = tid >> 4;
    const int px   = (q & 3) * 4;
    const int pyo  = q >> 2;
    unsigned char* const ldsA_w = ldsA + r0 * 128 + ((q * 8) ^ ((r0 & 7) << 4));

    int arow[4];
    #pragma unroll
    for (int it = 0; it < 4; ++it) {
        const int m  = bm * BM + r0 + it * 16;
        const int b  = m / Lp;
        const int li = m - b * Lp;
        const int gy = li / GWp;
        const int gx = li - gy * GWp;
        arow[it] = b * (Cch * Him * Wim) + (gy * PB) * Wim + gx * PB;
    }

    // ---- B fragment base: col-groups g = bn*24 + wc*6 + fj, k-chunk t*2+kk
    const __bf16* const wfw = Wf + (size_t)(bn * 24 + wc * 6) * NKC * 512 + lane * 8;

    f32x4 pa[4];

    auto load_A = [&](int t) {
        const int c   = t >> 2;
        const int pyb = (t & 3) * 4;
        const float* xs = x + c * (Him * Wim) + (pyb + pyo) * Wim + px;
        #pragma unroll
        for (int it = 0; it < 4; ++it)
            pa[it] = *(const f32x4*)(xs + arow[it]);
    };

    auto store_A = [&]() {
        #pragma unroll
        for (int it = 0; it < 4; ++it) {
            bf16x4 ha;
            #pragma unroll
            for (int e = 0; e < 4; ++e) ha[e] = (__bf16)pa[it][e];
            *(bf16x4*)(ldsA_w + it * 2048) = ha;   // 16 rows * 128 B
        }
    };

    f32x4 acc[4][6];
    #pragma unroll
    for (int i = 0; i < 4; ++i)
        #pragma unroll
        for (int j = 0; j < 6; ++j)
            acc[i][j] = f32x4{0.f, 0.f, 0.f, 0.f};

    const int arowb = fr * 128;
    const int sw    = (fr & 7) << 4;

    auto compute = [&](int t) {
        #pragma unroll
        for (int kk = 0; kk < 2; ++kk) {
            // 6 B fragments straight from L2 (coalesced 1024-B frags)
            bf16x8 br[6];
            #pragma unroll
            for (int fj = 0; fj < 6; ++fj)
                br[fj] = *(const bf16x8*)(wfw + (fj * NKC + t * 2 + kk) * 512);
            const int kb = (kk * 64 + kg * 16) ^ sw;   // bits 4-6 only
            #pragma unroll
            for (int fi = 0; fi < 4; ++fi) {
                const bf16x8 ar = *(const bf16x8*)(ldsA + arowb + fi * 2048 + kb);
                #pragma unroll
                for (int fj = 0; fj < 6; ++fj)
                    acc[fi][fj] = __builtin_amdgcn_mfma_f32_16x16x32_bf16(
                        ar, br[fj], acc[fi][fj], 0, 0, 0);
            }
        }
    };

    // ---- main loop: single A buffer, 2 barriers/K-step, issue-early loads
    load_A(0);
    for (int t = 0; t < NT; ++t) {
        __syncthreads();               // all reads of tile t-1 done
        store_A();                     // cvt + ds_write A(t)
        __syncthreads();               // A(t) visible
        if (t + 1 < NT) load_A(t + 1); // in flight under compute(t)
        compute(t);
    }

    // epilogue: C/D layout col = lane&15, row = (lane>>4)*4 + j
    const int orow0 = bm * BM;
    const int ocol0 = bn * BN + wc * 96;
    #pragma unroll
    for (int fj = 0; fj < 6; ++fj) {
        const int col = ocol0 + fj * 16 + fr;
        const float bv = bias[col];
        #pragma unroll
        for (int fi = 0; fi < 4; ++fi) {
            const int row = orow0 + fi * 16 + kg * 4;
            #pragma unroll
            for (int j = 0; j < 4; ++j)
                out[(row + j) * Nd + col] = acc[fi][fj][j] + bv;
        }
    }
}

} // namespace

extern "C" void kernel_launch(void* const* d_in, const int* in_sizes, int n_in,
                              void* d_out, int out_size, void* d_ws, size_t ws_size,
                              hipStream_t stream)
{
    (void)in_sizes; (void)n_in; (void)out_size; (void)ws_size;
    const float* x  = (const float*)d_in[0];
    const float* Wm = (const float*)d_in[1];
    const float* bs = (const float*)d_in[2];
    float* outp = (float*)d_out;
    __bf16* Wf = (__bf16*)d_ws;   // 768*768*2 B, fragment-ordered

    pack_w<<<dim3(Kd * Nd / (256 * 8)), dim3(256), 0, stream>>>(Wm, Wf);
    patch_embed_gemm<<<dim3(NBLK), dim3(256), 0, stream>>>(x, Wf, bs, outp);
}